// Round 1
// baseline (349.983 us; speedup 1.0000x reference)
//
#include <hip/hip_runtime.h>
#include <hip/hip_bf16.h>
#include <stdint.h>

#define NN 4096
#define EMB 300
#define KPAD 320

typedef __attribute__((ext_vector_type(8))) short short8;
typedef __attribute__((ext_vector_type(4))) float f32x4;

// ---------------------------------------------------------------------------
// Kernel A: projection  f = l2norm(relu(h@W1+b1)@W2+b2), split to bf16 hi/lo
// grid 512 blocks x 320 threads; block handles 16 rows; thread = one column.
// ---------------------------------------------------------------------------
__global__ __launch_bounds__(320) void proj_kernel(
    const float* __restrict__ h0, const float* __restrict__ h1,
    const float* __restrict__ W1, const float* __restrict__ b1,
    const float* __restrict__ W2, const float* __restrict__ b2,
    unsigned short* __restrict__ f0hi, unsigned short* __restrict__ f0lo,
    unsigned short* __restrict__ f1hi, unsigned short* __restrict__ f1lo)
{
    __shared__ float hs[16][EMB];
    __shared__ float ys[16][EMB];
    __shared__ float wred[5][16];
    __shared__ float scale_s[16];

    const int tid  = threadIdx.x;
    const int wave = tid >> 6;
    const int lane = tid & 63;
    const int blk  = blockIdx.x;
    const int half = blk >> 8;               // 0 -> h0, 1 -> h1
    const int row0 = (blk & 255) * 16;
    const float* __restrict__ H = half ? h1 : h0;
    unsigned short* __restrict__ FHI = half ? f1hi : f0hi;
    unsigned short* __restrict__ FLO = half ? f1lo : f0lo;

    for (int idx = tid; idx < 16 * EMB; idx += 320) {
        int r = idx / EMB, c = idx - r * EMB;
        hs[r][c] = H[(size_t)(row0 + r) * EMB + c];
    }
    __syncthreads();

    const int j = tid;
    float acc[16];

    if (j < EMB) {                                   // layer 1
        float bb = b1[j];
        #pragma unroll
        for (int r = 0; r < 16; ++r) acc[r] = bb;
        for (int k = 0; k < EMB; ++k) {
            float w = W1[(size_t)k * EMB + j];
            #pragma unroll
            for (int r = 0; r < 16; ++r) acc[r] = fmaf(hs[r][k], w, acc[r]);
        }
        #pragma unroll
        for (int r = 0; r < 16; ++r) ys[r][j] = fmaxf(acc[r], 0.f);
    }
    __syncthreads();

    float z[16];
    #pragma unroll
    for (int r = 0; r < 16; ++r) z[r] = 0.f;
    if (j < EMB) {                                   // layer 2
        float bb = b2[j];
        #pragma unroll
        for (int r = 0; r < 16; ++r) acc[r] = bb;
        for (int k = 0; k < EMB; ++k) {
            float w = W2[(size_t)k * EMB + j];
            #pragma unroll
            for (int r = 0; r < 16; ++r) acc[r] = fmaf(ys[r][k], w, acc[r]);
        }
        #pragma unroll
        for (int r = 0; r < 16; ++r) z[r] = acc[r];
    }

    // per-row squared-norm reduce (all threads participate; pad lanes add 0)
    float pz[16];
    #pragma unroll
    for (int r = 0; r < 16; ++r) pz[r] = z[r] * z[r];
    #pragma unroll
    for (int off = 32; off >= 1; off >>= 1) {
        #pragma unroll
        for (int r = 0; r < 16; ++r) pz[r] += __shfl_down(pz[r], off, 64);
    }
    if (lane == 0) {
        #pragma unroll
        for (int r = 0; r < 16; ++r) wred[wave][r] = pz[r];
    }
    __syncthreads();
    if (tid < 16) {
        float s = 0.f;
        #pragma unroll
        for (int w = 0; w < 5; ++w) s += wred[w][tid];
        scale_s[tid] = 1.0f / fmaxf(sqrtf(s), 1e-12f);
    }
    __syncthreads();

    if (j < EMB) {
        #pragma unroll
        for (int r = 0; r < 16; ++r) {
            float f = z[r] * scale_s[r];
            __hip_bfloat16 hb = __float2bfloat16(f);
            float hf = __bfloat162float(hb);
            __hip_bfloat16 lb = __float2bfloat16(f - hf);
            size_t o = (size_t)(row0 + r) * KPAD + j;
            FHI[o] = *reinterpret_cast<unsigned short*>(&hb);
            FLO[o] = *reinterpret_cast<unsigned short*>(&lb);
        }
    } else {                                          // zero the K-padding
        #pragma unroll
        for (int r = 0; r < 16; ++r) {
            size_t o = (size_t)(row0 + r) * KPAD + j;
            FHI[o] = 0; FLO[o] = 0;
        }
    }
}

// ---------------------------------------------------------------------------
// Kernel B: S0 = exp((f0 f1^T)/T) + eps  via split-bf16 MFMA (hi*hi+hi*lo+lo*hi)
// 128x128 tile, 4 waves (2x2), 16x16x32 MFMA, global_load_lds width-16 staging.
// Epilogue also accumulates column sums (Sinkhorn iteration i=0) into tcol.
// ---------------------------------------------------------------------------
#define BM 128
#define BN 128
#define BK 32

__global__ __launch_bounds__(256) void gemm_exp_kernel(
    const unsigned short* __restrict__ Ahi, const unsigned short* __restrict__ Alo,
    const unsigned short* __restrict__ Bhi, const unsigned short* __restrict__ Blo,
    float* __restrict__ S, float* __restrict__ tcol)
{
    __shared__ unsigned short lA[2][BM * BK];
    __shared__ unsigned short lB[2][BN * BK];
    __shared__ float colsum[BN];

    const int tid  = threadIdx.x;
    const int wave = tid >> 6;
    const int lane = tid & 63;
    const int bx   = blockIdx.x & 31;
    const int by   = blockIdx.x >> 5;
    const int brow = by * BM, bcol = bx * BN;
    const int wm   = wave >> 1, wn = wave & 1;
    const int frow = lane & 15;
    const int kgrp = lane >> 4;

    f32x4 acc[4][4];
    #pragma unroll
    for (int m = 0; m < 4; ++m)
        #pragma unroll
        for (int n = 0; n < 4; ++n) acc[m][n] = (f32x4)0.f;

    // each wave stages one of the 4 buffers
    const unsigned short* gbase = (wave == 0) ? Ahi : (wave == 1) ? Alo
                                 : (wave == 2) ? Bhi : Blo;
    unsigned short* lbase = (wave == 0) ? lA[0] : (wave == 1) ? lA[1]
                           : (wave == 2) ? lB[0] : lB[1];
    const int rb   = (wave < 2) ? brow : bcol;
    const int srow = lane >> 2;          // 0..15
    const int scol = (lane & 3) * 8;     // element offset in K

    for (int kt = 0; kt < KPAD / BK; ++kt) {
        const int k0 = kt * BK;
        __syncthreads();
        #pragma unroll
        for (int c = 0; c < 8; ++c) {
            const unsigned short* g =
                gbase + (size_t)(rb + c * 16 + srow) * KPAD + k0 + scol;
            __builtin_amdgcn_global_load_lds(
                (const __attribute__((address_space(1))) void*)g,
                (__attribute__((address_space(3))) void*)(lbase + c * 512),
                16, 0, 0);
        }
        __syncthreads();

        short8 ahi[4], alo[4], bhi[4], blo[4];
        #pragma unroll
        for (int m = 0; m < 4; ++m) {
            int r = wm * 64 + m * 16 + frow;
            ahi[m] = *(const short8*)(lA[0] + r * BK + kgrp * 8);
            alo[m] = *(const short8*)(lA[1] + r * BK + kgrp * 8);
        }
        #pragma unroll
        for (int n = 0; n < 4; ++n) {
            int r = wn * 64 + n * 16 + frow;
            bhi[n] = *(const short8*)(lB[0] + r * BK + kgrp * 8);
            blo[n] = *(const short8*)(lB[1] + r * BK + kgrp * 8);
        }
        #pragma unroll
        for (int m = 0; m < 4; ++m)
            #pragma unroll
            for (int n = 0; n < 4; ++n) {
                acc[m][n] = __builtin_amdgcn_mfma_f32_16x16x32_bf16(ahi[m], bhi[n], acc[m][n], 0, 0, 0);
                acc[m][n] = __builtin_amdgcn_mfma_f32_16x16x32_bf16(ahi[m], blo[n], acc[m][n], 0, 0, 0);
                acc[m][n] = __builtin_amdgcn_mfma_f32_16x16x32_bf16(alo[m], bhi[n], acc[m][n], 0, 0, 0);
            }
    }

    if (tid < BN) colsum[tid] = 0.f;
    __syncthreads();

    const float SCALE = 36.067376022224085f;  // log2(e)/0.04
    #pragma unroll
    for (int n = 0; n < 4; ++n) {
        const int col = bcol + wn * 64 + n * 16 + frow;
        float cp = 0.f;
        #pragma unroll
        for (int m = 0; m < 4; ++m) {
            const int rbase = brow + wm * 64 + m * 16 + kgrp * 4;
            f32x4 a = acc[m][n];
            #pragma unroll
            for (int q = 0; q < 4; ++q) {
                float sv = exp2f(a[q] * SCALE) + 1e-10f;
                S[(size_t)(rbase + q) * NN + col] = sv;
                cp += sv;
            }
        }
        atomicAdd(&colsum[wn * 64 + n * 16 + frow], cp);
    }
    __syncthreads();
    if (tid < BN) atomicAdd(&tcol[bcol + tid], colsum[tid]);
}

// ---------------------------------------------------------------------------
// Sinkhorn passes.  s_k = diag(u) S0 diag(v):
//   row pass: u_i = 1/sum_j S0_ij v_j        col pass: t_j += sum_i u_i S0_ij
// ---------------------------------------------------------------------------
#define RROWS 8
__global__ __launch_bounds__(256) void row_pass(
    const float* __restrict__ S, const float* __restrict__ v, float* __restrict__ u)
{
    __shared__ float vs[NN];
    __shared__ float red[RROWS][4];
    const int tid = threadIdx.x;
    const int wave = tid >> 6, lane = tid & 63;
    for (int i = tid; i < NN / 4; i += 256)
        ((float4*)vs)[i] = ((const float4*)v)[i];
    __syncthreads();
    const int row0 = blockIdx.x * RROWS;
    for (int rr = 0; rr < RROWS; ++rr) {
        const float4* rowp = (const float4*)(S + (size_t)(row0 + rr) * NN);
        float part = 0.f;
        #pragma unroll 4
        for (int c4 = tid; c4 < NN / 4; c4 += 256) {
            float4 sv = rowp[c4];
            float4 vv = ((const float4*)vs)[c4];
            part += sv.x * vv.x + sv.y * vv.y + sv.z * vv.z + sv.w * vv.w;
        }
        #pragma unroll
        for (int off = 32; off >= 1; off >>= 1) part += __shfl_down(part, off, 64);
        if (lane == 0) red[rr][wave] = part;
    }
    __syncthreads();
    if (tid < RROWS) {
        float rs = red[tid][0] + red[tid][1] + red[tid][2] + red[tid][3];
        u[row0 + tid] = 1.0f / rs;
    }
}

#define CROWS 32
__global__ __launch_bounds__(256) void col_pass(
    const float* __restrict__ S, const float* __restrict__ u, float* __restrict__ t)
{
    __shared__ float us[CROWS];
    const int tid = threadIdx.x;
    const int cb = blockIdx.x & 3;
    const int rbk = blockIdx.x >> 2;
    const int col0 = cb * 1024 + tid * 4;
    const int row0 = rbk * CROWS;
    if (tid < CROWS) us[tid] = u[row0 + tid];
    __syncthreads();
    float a0 = 0, a1 = 0, a2 = 0, a3 = 0;
    #pragma unroll 8
    for (int r = 0; r < CROWS; ++r) {
        float4 sv = *(const float4*)(S + (size_t)(row0 + r) * NN + col0);
        float ur = us[r];
        a0 = fmaf(sv.x, ur, a0);
        a1 = fmaf(sv.y, ur, a1);
        a2 = fmaf(sv.z, ur, a2);
        a3 = fmaf(sv.w, ur, a3);
    }
    atomicAdd(&t[col0 + 0], a0);
    atomicAdd(&t[col0 + 1], a1);
    atomicAdd(&t[col0 + 2], a2);
    atomicAdd(&t[col0 + 3], a3);
}

__global__ __launch_bounds__(256) void fix_kernel(float* __restrict__ t, float* __restrict__ v)
{
    int i = blockIdx.x * 256 + threadIdx.x;
    v[i] = 1.0f / t[i];
    t[i] = 0.f;   // re-zero for the next col accumulation
}

// final: u_i = 1/(row . v); out_ij = u_i * S0_ij * v_j  (in place)
__global__ __launch_bounds__(256) void final_kernel(
    float* __restrict__ S, const float* __restrict__ v)
{
    __shared__ float vs[NN];
    __shared__ float red[4];
    const int tid = threadIdx.x;
    const int wave = tid >> 6, lane = tid & 63;
    for (int i = tid; i < NN / 4; i += 256)
        ((float4*)vs)[i] = ((const float4*)v)[i];
    __syncthreads();
    const int row0 = blockIdx.x * RROWS;
    for (int rr = 0; rr < RROWS; ++rr) {
        float4* rowp = (float4*)(S + (size_t)(row0 + rr) * NN);
        float4 rv[4];
        float part = 0.f;
        #pragma unroll
        for (int ii = 0; ii < 4; ++ii) {
            int c4 = tid + 256 * ii;
            rv[ii] = rowp[c4];
            float4 vv = ((const float4*)vs)[c4];
            part += rv[ii].x * vv.x + rv[ii].y * vv.y + rv[ii].z * vv.z + rv[ii].w * vv.w;
        }
        #pragma unroll
        for (int off = 32; off >= 1; off >>= 1) part += __shfl_down(part, off, 64);
        if (lane == 0) red[wave] = part;
        __syncthreads();
        float ui = 1.0f / (red[0] + red[1] + red[2] + red[3]);
        #pragma unroll
        for (int ii = 0; ii < 4; ++ii) {
            int c4 = tid + 256 * ii;
            float4 vv = ((const float4*)vs)[c4];
            float4 o;
            o.x = rv[ii].x * ui * vv.x;
            o.y = rv[ii].y * ui * vv.y;
            o.z = rv[ii].z * ui * vv.z;
            o.w = rv[ii].w * ui * vv.w;
            rowp[c4] = o;
        }
        __syncthreads();
    }
}

// ---------------------------------------------------------------------------
extern "C" void kernel_launch(void* const* d_in, const int* in_sizes, int n_in,
                              void* d_out, int out_size, void* d_ws, size_t ws_size,
                              hipStream_t stream)
{
    (void)in_sizes; (void)n_in; (void)out_size; (void)ws_size;
    const float* h0 = (const float*)d_in[0];
    const float* h1 = (const float*)d_in[1];
    const float* W1 = (const float*)d_in[2];
    const float* b1 = (const float*)d_in[3];
    const float* W2 = (const float*)d_in[4];
    const float* b2 = (const float*)d_in[5];
    float* S = (float*)d_out;      // S0 lives in the output buffer

    char* ws = (char*)d_ws;
    const size_t FSZ = (size_t)NN * KPAD * sizeof(unsigned short);
    unsigned short* f0hi = (unsigned short*)(ws);
    unsigned short* f0lo = (unsigned short*)(ws + FSZ);
    unsigned short* f1hi = (unsigned short*)(ws + 2 * FSZ);
    unsigned short* f1lo = (unsigned short*)(ws + 3 * FSZ);
    float* u = (float*)(ws + 4 * FSZ);
    float* v = (float*)(ws + 4 * FSZ + NN * sizeof(float));
    float* t = (float*)(ws + 4 * FSZ + 2 * NN * sizeof(float));

    hipMemsetAsync(t, 0, NN * sizeof(float), stream);
    proj_kernel<<<512, 320, 0, stream>>>(h0, h1, W1, b1, W2, b2, f0hi, f0lo, f1hi, f1lo);
    gemm_exp_kernel<<<1024, 256, 0, stream>>>(f0hi, f0lo, f1hi, f1lo, S, t);  // + i=0 colsums
    fix_kernel<<<16, 256, 0, stream>>>(t, v);                                  // v = 1/t
    for (int it = 0; it < 4; ++it) {
        row_pass<<<512, 256, 0, stream>>>(S, v, u);    // i = 1,3,5,7
        col_pass<<<512, 256, 0, stream>>>(S, u, t);    // i = 2,4,6,8
        fix_kernel<<<16, 256, 0, stream>>>(t, v);
    }
    final_kernel<<<512, 256, 0, stream>>>(S, v);        // i = 9 + output write
}